// Round 5
// baseline (97.500 us; speedup 1.0000x reference)
//
#include <hip/hip_runtime.h>
#include <math.h>

#define CC   256
#define SP   8                 // floats per LDS element slot (32B = 2x float4)
#define NY   (CC + 33)         // y needed on [0, C+32]
#define NZ   (CC + 25)         // k1 / z2 range
#define NK2  (CC + 17)         // k2 / z3 range
#define NK3  (CC + 9)          // k3 / z4 range
#define ISCL 0.0125f           // INTERACTION_SCALE / len(SHIFTS)

// ============================================================================
// Cl(3,0) ~= M2(C) via Pauli matrices:  e1->s1, e2->s2, e3->s3,
// e12 = i s3, e13 = -i s2, e23 = i s1, e123 = i I.
// Multivector a[8] (basis [1,e1,e2,e3,e12,e13,e23,e123]) <-> matrix
//   M = [[ (a0+a3)+i(a7+a4) , (a1-a5)+i(a6-a2) ],
//        [ (a1+a5)+i(a6+a2) , (a0-a3)+i(a7-a4) ]]
// stored as float m[8] = {M00r,M00i, M01r,M01i, M10r,M10i, M11r,M11i}.
// ============================================================================

// ---------------- complex primitives ----------------
__device__ __forceinline__ void cmul(float& orr, float& oi,
                                     float ar, float ai, float br, float bi) {
    orr = fmaf(ar, br, -(ai * bi));
    oi  = fmaf(ar, bi,   ai * br);
}
__device__ __forceinline__ void cmad(float& orr, float& oi,
                                     float ar, float ai, float br, float bi) {
    orr = fmaf(ar, br, fmaf(-ai, bi, orr));
    oi  = fmaf(ar, bi, fmaf( ai, br, oi));
}
__device__ __forceinline__ void cmsub(float& orr, float& oi,
                                      float ar, float ai, float br, float bi) {
    orr = fmaf(-ar, br, fmaf( ai, bi, orr));
    oi  = fmaf(-ar, bi, fmaf(-ai, br, oi));
}

// o = a * b  (2x2 complex matmul, 32 FMA)
__device__ __forceinline__ void mm2(const float* a, const float* b, float* o) {
    float r0,r1,r2,r3,r4,r5,r6,r7;
    cmul(r0,r1, a[0],a[1], b[0],b[1]); cmad(r0,r1, a[2],a[3], b[4],b[5]);
    cmul(r2,r3, a[0],a[1], b[2],b[3]); cmad(r2,r3, a[2],a[3], b[6],b[7]);
    cmul(r4,r5, a[4],a[5], b[0],b[1]); cmad(r4,r5, a[6],a[7], b[4],b[5]);
    cmul(r6,r7, a[4],a[5], b[2],b[3]); cmad(r6,r7, a[6],a[7], b[6],b[7]);
    o[0]=r0; o[1]=r1; o[2]=r2; o[3]=r3; o[4]=r4; o[5]=r5; o[6]=r6; o[7]=r7;
}

// ---------------- commutator (traceless operands) ----------------
// [A,W] with A traceless (u6 = {A00, A01, A10}); W given by off-diagonals
// W01, W10 and diagonal difference dW = W00 - W11. Result traceless:
//   C00 = A01*W10 - A10*W01 ; C01 = W01*dA - A01*dW ; C10 = A10*dW - W10*dA
// where dA = 2*A00.
__device__ __forceinline__ void comm_core2(const float* u6,
        float w01r, float w01i, float w10r, float w10i,
        float dwr, float dwi, float* o6) {
    const float dar = 2.f * u6[0], dai = 2.f * u6[1];
    float ar, ai;
    cmul (ar, ai, u6[2],u6[3], w10r,w10i);     // A01*W10
    cmsub(ar, ai, u6[4],u6[5], w01r,w01i);     // - A10*W01
    o6[0] = ar; o6[1] = ai;
    cmul (ar, ai, w01r,w01i, dar,dai);         // W01*dA
    cmsub(ar, ai, u6[2],u6[3], dwr,dwi);       // - A01*dW
    o6[2] = ar; o6[3] = ai;
    cmul (ar, ai, u6[4],u6[5], dwr,dwi);       // A10*dW
    cmsub(ar, ai, w10r,w10i, dar,dai);         // - W10*dA
    o6[4] = ar; o6[5] = ai;
}

// dexp^{-1}_{s*k}(w), order 4, Bernoulli (1,-1/2,1/6,0,-1/30).
// Central part of k commutes with everything -> use traceless part only;
// scale s folded into coefficients (ad_{sk}^n = s^n ad_k^n).
// Incremental accumulation to minimize live temps.
__device__ __forceinline__ void dexpinv8(const float* k, const float* w,
                                         float s, float* o) {
    float u6[6];
    u6[0] = 0.5f*(k[0]-k[6]); u6[1] = 0.5f*(k[1]-k[7]);
    u6[2] = k[2]; u6[3] = k[3]; u6[4] = k[4]; u6[5] = k[5];
    const float s2 = s*s;
    const float c1 = -0.5f*s, c2 = s2*(1.f/12.f), c4 = -(s2*s2)*(1.f/720.f);
    float cur[6], nxt[6], acc[6];
    comm_core2(u6, w[2],w[3], w[4],w[5], w[0]-w[6], w[1]-w[7], cur);   // ad^1
#pragma unroll
    for (int c = 0; c < 6; ++c) acc[c] = c1 * cur[c];
    comm_core2(u6, cur[2],cur[3], cur[4],cur[5], 2.f*cur[0], 2.f*cur[1], nxt); // ad^2
#pragma unroll
    for (int c = 0; c < 6; ++c) { acc[c] = fmaf(c2, nxt[c], acc[c]); cur[c] = nxt[c]; }
    comm_core2(u6, cur[2],cur[3], cur[4],cur[5], 2.f*cur[0], 2.f*cur[1], nxt); // ad^3 (B3=0)
#pragma unroll
    for (int c = 0; c < 6; ++c) cur[c] = nxt[c];
    comm_core2(u6, cur[2],cur[3], cur[4],cur[5], 2.f*cur[0], 2.f*cur[1], nxt); // ad^4
#pragma unroll
    for (int c = 0; c < 6; ++c) acc[c] = fmaf(c4, nxt[c], acc[c]);
    o[0] = w[0] + acc[0]; o[1] = w[1] + acc[1];
    o[2] = w[2] + acc[2]; o[3] = w[3] + acc[3];
    o[4] = w[4] + acc[4]; o[5] = w[5] + acc[5];
    o[6] = w[6] - acc[0]; o[7] = w[7] - acc[1];
}

// ---------------- closed-form exp ----------------
// exp(s*k) = e^{c0} (cosh(d) I + sinhc(d) V), c0 = central part, V traceless,
// d^2 = w = V00^2 + V01*V10. cosh/sinhc as entire series in w.
// FAST (z-stages, |w| <~ 0.3): 3 terms, trunc err <= w^3/720 ~ 4e-5.
// FULL (final exp, clipped u):  5 terms, err <= |w|^5/10! (|w|<=~5 -> 3e-4 worst).
__device__ __forceinline__ void chstep(float& pr, float& pi,
                                       float wr, float wi, float K) {
    const float nr = fmaf(pr, wr, fmaf(-pi, wi, K));
    const float ni = fmaf(pr, wi, pi * wr);
    pr = nr; pi = ni;
}
template<bool FULL>
__device__ __forceinline__ void expm(const float* k, float s, float* o) {
    const float hs = 0.5f * s;
    const float c0r = hs*(k[0]+k[6]), c0i = hs*(k[1]+k[7]);
    const float v0r = hs*(k[0]-k[6]), v0i = hs*(k[1]-k[7]);
    const float v1r = s*k[2], v1i = s*k[3];
    const float v2r = s*k[4], v2i = s*k[5];
    float wr = fmaf(v0r, v0r, -(v0i*v0i));
    wr = fmaf(v1r, v2r, wr); wr = fmaf(-v1i, v2i, wr);
    float wi = 2.f*v0r*v0i;
    wi = fmaf(v1r, v2i, wi); wi = fmaf(v1i, v2r, wi);
    float Cr, Ci = 0.f, Sr, Si = 0.f;
    if (FULL) {
        Cr = 1.f/40320.f;                      // cosh: 1,1/2,1/24,1/720,1/40320
        chstep(Cr, Ci, wr, wi, 1.f/720.f);
        chstep(Cr, Ci, wr, wi, 1.f/24.f);
        chstep(Cr, Ci, wr, wi, 0.5f);
        chstep(Cr, Ci, wr, wi, 1.f);
        Sr = 1.f/362880.f;                     // sinhc: 1,1/6,1/120,1/5040,1/362880
        chstep(Sr, Si, wr, wi, 1.f/5040.f);
        chstep(Sr, Si, wr, wi, 1.f/120.f);
        chstep(Sr, Si, wr, wi, 1.f/6.f);
        chstep(Sr, Si, wr, wi, 1.f);
    } else {
        Cr = 1.f/24.f;                         // cosh: 1,1/2,1/24
        chstep(Cr, Ci, wr, wi, 0.5f);
        chstep(Cr, Ci, wr, wi, 1.f);
        Sr = 1.f/120.f;                        // sinhc: 1,1/6,1/120
        chstep(Sr, Si, wr, wi, 1.f/6.f);
        chstep(Sr, Si, wr, wi, 1.f);
    }
    const float ex = __expf(c0r);
    const float cs = __cosf(c0i), sn = __sinf(c0i);
    const float er = ex*cs, ei = ex*sn;        // e^{c0}
    float p0r, p0i; cmul(p0r, p0i, Sr, Si, v0r, v0i);     // S*V00
    const float tr = Cr + p0r, ti = Ci + p0i;
    const float ur = Cr - p0r, ui = Ci - p0i;
    cmul(o[0], o[1], er, ei, tr, ti);
    cmul(o[6], o[7], er, ei, ur, ui);
    float qr, qi; cmul(qr, qi, er, ei, Sr, Si);           // e^{c0}*S
    cmul(o[2], o[3], qr, qi, v1r, v1i);
    cmul(o[4], o[5], qr, qi, v2r, v2i);
}

// ---------------- LDS access (b128-vectorized, bank-swizzled) ----------------
__device__ __forceinline__ int sbase(int e) { return (e << 3) ^ (e & 4); }

__device__ __forceinline__ void lds_load8(const float* buf, int e, float* o) {
    const int b = sbase(e);
    float4 a = *(const float4*)(buf + b);
    float4 c = *(const float4*)(buf + (b ^ 4));
    o[0] = a.x; o[1] = a.y; o[2] = a.z; o[3] = a.w;
    o[4] = c.x; o[5] = c.y; o[6] = c.z; o[7] = c.w;
}
__device__ __forceinline__ void lds_store8(float* buf, int e, const float* v) {
    const int b = sbase(e);
    *(float4*)(buf + b)       = make_float4(v[0], v[1], v[2], v[3]);
    *(float4*)(buf + (b ^ 4)) = make_float4(v[4], v[5], v[6], v[7]);
}

// vector_field (matrix rep): derivative map + ISCL * z0 * bc
__device__ __forceinline__ void vf8_lds(const float* buf, int e, float* o) {
    float z0[8], t1[8], t2[8], t4[8], t8[8], bc[8], g[8];
    lds_load8(buf, e,     z0);
    lds_load8(buf, e + 1, t1);
    lds_load8(buf, e + 2, t2);
    lds_load8(buf, e + 4, t4);
    lds_load8(buf, e + 8, t8);
#pragma unroll
    for (int c = 0; c < 8; ++c)
        bc[c] = fmaf(0.125f, t8[c], fmaf(0.25f, t4[c], fmaf(0.5f, t2[c], t1[c])));
    mm2(z0, bc, g);
    const float Sr  = z0[2]+z0[4], Si  = z0[3]+z0[5];   // M01+M10
    const float Ddr = z0[0]-z0[6], Ddi = z0[1]-z0[7];   // M00-M11
    const float Tr  = z0[4]-z0[2], Ti  = z0[5]-z0[3];   // M10-M01
    o[0] = fmaf(ISCL, g[0],  0.5f*Si);
    o[1] = fmaf(ISCL, g[1], -0.5f*Sr);
    o[2] = fmaf(ISCL, g[2],  0.5f*(Ddi+Ti));
    o[3] = fmaf(ISCL, g[3], -0.5f*(Ddr+Tr));
    o[4] = fmaf(ISCL, g[4],  0.5f*(Ddi-Ti));
    o[5] = fmaf(ISCL, g[5], -0.5f*(Ddr-Tr));
    o[6] = fmaf(ISCL, g[6], -0.5f*Si);
    o[7] = fmaf(ISCL, g[7],  0.5f*Sr);
}

// z = exp(scale*k) * y[e] -> zbuf[e]  (fast 3-term exp: z-stage scales only)
__device__ __forceinline__ void zstage(const float* ybuf, float* zbuf, int e,
                                       const float* k, float scale) {
    float ex[8], yv[8], o[8];
    expm<false>(k, scale, ex);
    lds_load8(ybuf, e, yv);
    mm2(ex, yv, o);
    lds_store8(zbuf, e, o);
}

// kout = dexpinv(scale*kin, vf(z[e]))
__device__ __forceinline__ void kstage(const float* zbuf, int e,
                                       const float* kin, float scale, float* kout) {
    float w[8];
    vf8_lds(zbuf, e, w);
    dexpinv8(kin, w, scale, kout);
}

__global__ __launch_bounds__(CC, 5)
void clifford_step_kernel(const float* __restrict__ y, float* __restrict__ out) {
    __shared__ __align__(16) float sy[NY * SP];   // 9248 B (matrix rep)
    __shared__ __align__(16) float sz[NZ * SP];   // 8992 B

    const int tid   = threadIdx.x;
    const int row   = blockIdx.x >> 8;      // 65536/256 = 256 chunks per row
    const int chunk = blockIdx.x & 255;
    const int base  = chunk * CC;
    // rotate the halo-heavy wave per block so heavy waves spread across SIMDs
    const int bt    = (tid - ((blockIdx.x & 3) << 6)) & 255;
    const float* __restrict__ yrow = y + (size_t)row * 65536u * 8u;

    // ---- load y tile (+halo 32) into LDS, converting mv -> matrix ----
    {
        const int g0 = (base + tid) & 65535;
        const float4* p = (const float4*)(yrow + (size_t)g0 * 8u);
        float4 A = p[0], B = p[1];     // a0..a3 | a4..a7
        const int s = sbase(tid);
        *(float4*)&sy[s]     = make_float4(A.x + A.w, B.w + B.x, A.y - B.y, B.z - A.z);
        *(float4*)&sy[s ^ 4] = make_float4(A.y + B.y, B.z + A.z, A.x - A.w, B.w - B.x);
        if (bt < NY - CC) {
            const int e  = CC + bt;
            const int g1 = (base + e) & 65535;
            const float4* q = (const float4*)(yrow + (size_t)g1 * 8u);
            float4 Cv = q[0], D = q[1];
            const int s2 = sbase(e);
            *(float4*)&sy[s2]     = make_float4(Cv.x + Cv.w, D.w + D.x, Cv.y - D.y, D.z - Cv.z);
            *(float4*)&sy[s2 ^ 4] = make_float4(Cv.y + D.y, D.z + Cv.z, Cv.x - Cv.w, D.w - D.x);
        }
    }
    __syncthreads();

    // ---- rolling state: ka/kb = current k, uacc = k1 + 2k2 + 2k3 (+k4) ----
    float ka[8], kb[8], uacc[8], kn[8];

    // k1
    vf8_lds(sy, tid, ka);
#pragma unroll
    for (int c = 0; c < 8; ++c) uacc[c] = ka[c];
    if (bt < NZ - CC) vf8_lds(sy, CC + bt, kb);

    // z2 = exp(0.05*k1) * y
    zstage(sy, sz, tid, ka, 0.05f);
    if (bt < NZ - CC) zstage(sy, sz, CC + bt, kb, 0.05f);
    __syncthreads();                         // RAW on sz

    // k2 = dexpinv(0.05*k1, vf(z2))
    kstage(sz, tid, ka, 0.05f, kn);
#pragma unroll
    for (int c = 0; c < 8; ++c) { ka[c] = kn[c]; uacc[c] = fmaf(2.f, kn[c], uacc[c]); }
    if (bt < NK2 - CC) {
        kstage(sz, CC + bt, kb, 0.05f, kn);
#pragma unroll
        for (int c = 0; c < 8; ++c) kb[c] = kn[c];
    }
    __syncthreads();                         // WAR: z3 overwrites sz

    // z3 = exp(0.05*k2) * y
    zstage(sy, sz, tid, ka, 0.05f);
    if (bt < NK2 - CC) zstage(sy, sz, CC + bt, kb, 0.05f);
    __syncthreads();                         // RAW on sz

    // k3 = dexpinv(0.05*k2, vf(z3))
    kstage(sz, tid, ka, 0.05f, kn);
#pragma unroll
    for (int c = 0; c < 8; ++c) { ka[c] = kn[c]; uacc[c] = fmaf(2.f, kn[c], uacc[c]); }
    if (bt < NK3 - CC) {
        kstage(sz, CC + bt, kb, 0.05f, kn);
#pragma unroll
        for (int c = 0; c < 8; ++c) kb[c] = kn[c];
    }
    __syncthreads();                         // WAR: z4 overwrites sz

    // z4 = exp(0.1*k3) * y
    zstage(sy, sz, tid, ka, 0.1f);
    if (bt < NK3 - CC) zstage(sy, sz, CC + bt, kb, 0.1f);
    __syncthreads();                         // RAW on sz

    // ---- tail: k4, u (sanitized in mv basis), output ----
    {
        const int e = tid;
        float w[8], k4[8], um[8], ex[8], yv[8], om[8];
        vf8_lds(sz, e, w);
        dexpinv8(ka, w, 0.1f, k4);           // ka == k3

        const float s6 = 0.1f / 6.0f;
#pragma unroll
        for (int c = 0; c < 8; ++c)
            um[c] = s6 * (uacc[c] + k4[c]);
        // matrix -> multivector coeffs, nan_to_num + clip, -> matrix
        float av[8];
        av[0] = 0.5f*(um[0]+um[6]); av[3] = 0.5f*(um[0]-um[6]);
        av[7] = 0.5f*(um[1]+um[7]); av[4] = 0.5f*(um[1]-um[7]);
        av[1] = 0.5f*(um[2]+um[4]); av[5] = 0.5f*(um[4]-um[2]);
        av[6] = 0.5f*(um[3]+um[5]); av[2] = 0.5f*(um[5]-um[3]);
#pragma unroll
        for (int c = 0; c < 8; ++c) {
            float v = av[c];
            if (isnan(v)) v = 0.f;           // nan_to_num(nan=0); clip handles +-inf
            av[c] = fmaxf(-1.f, fminf(v, 1.f));
        }
        um[0] = av[0]+av[3]; um[1] = av[7]+av[4];
        um[2] = av[1]-av[5]; um[3] = av[6]-av[2];
        um[4] = av[1]+av[5]; um[5] = av[6]+av[2];
        um[6] = av[0]-av[3]; um[7] = av[7]-av[4];

        expm<true>(um, 1.f, ex);
        lds_load8(sy, e, yv);
        mm2(ex, yv, om);

        float* dst = out + ((size_t)row * 65536u + (size_t)(base + e)) * 8u;
        ((float4*)dst)[0] = make_float4(0.5f*(om[0]+om[6]), 0.5f*(om[2]+om[4]),
                                        0.5f*(om[5]-om[3]), 0.5f*(om[0]-om[6]));
        ((float4*)dst)[1] = make_float4(0.5f*(om[1]-om[7]), 0.5f*(om[4]-om[2]),
                                        0.5f*(om[3]+om[5]), 0.5f*(om[1]+om[7]));
    }
}

extern "C" void kernel_launch(void* const* d_in, const int* in_sizes, int n_in,
                              void* d_out, int out_size, void* d_ws, size_t ws_size,
                              hipStream_t stream) {
    const float* y = (const float*)d_in[0];
    float* out = (float*)d_out;
    dim3 grid(32 * 256);   // 32 rows x 256 chunks of 256 elements
    dim3 block(CC);
    hipLaunchKernelGGL(clifford_step_kernel, grid, block, 0, stream, y, out);
}

// Round 6
// 83.500 us; speedup vs baseline: 1.1677x; 1.1677x over previous
//
#include <hip/hip_runtime.h>
#include <math.h>

#define CC   256
#define SP   8                 // floats per LDS element slot (32B = 2x float4)
#define NY   (CC + 33)         // y needed on [0, C+32]
#define NZ   (CC + 25)         // k1 / z2 range
#define NK2  (CC + 17)         // k2 / z3 range
#define NK3  (CC + 9)          // k3 / z4 range
#define ISCL 0.0125f           // INTERACTION_SCALE / len(SHIFTS)

// ============================================================================
// Cl(3,0) ~= M2(C) via Pauli matrices:  e1->s1, e2->s2, e3->s3,
// e12 = i s3, e13 = -i s2, e23 = i s1, e123 = i I.
// Multivector a[8] (basis [1,e1,e2,e3,e12,e13,e23,e123]) <-> matrix
//   M = [[ (a0+a3)+i(a7+a4) , (a1-a5)+i(a6-a2) ],
//        [ (a1+a5)+i(a6+a2) , (a0-a3)+i(a7-a4) ]]
// stored as float m[8] = {M00r,M00i, M01r,M01i, M10r,M10i, M11r,M11i}.
// ============================================================================

// ---------------- complex primitives ----------------
__device__ __forceinline__ void cmul(float& orr, float& oi,
                                     float ar, float ai, float br, float bi) {
    orr = fmaf(ar, br, -(ai * bi));
    oi  = fmaf(ar, bi,   ai * br);
}
__device__ __forceinline__ void cmad(float& orr, float& oi,
                                     float ar, float ai, float br, float bi) {
    orr = fmaf(ar, br, fmaf(-ai, bi, orr));
    oi  = fmaf(ar, bi, fmaf( ai, br, oi));
}
__device__ __forceinline__ void cmsub(float& orr, float& oi,
                                      float ar, float ai, float br, float bi) {
    orr = fmaf(-ar, br, fmaf( ai, bi, orr));
    oi  = fmaf(-ar, bi, fmaf(-ai, br, oi));
}

// o = a * b  (2x2 complex matmul, 32 FMA)
__device__ __forceinline__ void mm2(const float* a, const float* b, float* o) {
    float r0,r1,r2,r3,r4,r5,r6,r7;
    cmul(r0,r1, a[0],a[1], b[0],b[1]); cmad(r0,r1, a[2],a[3], b[4],b[5]);
    cmul(r2,r3, a[0],a[1], b[2],b[3]); cmad(r2,r3, a[2],a[3], b[6],b[7]);
    cmul(r4,r5, a[4],a[5], b[0],b[1]); cmad(r4,r5, a[6],a[7], b[4],b[5]);
    cmul(r6,r7, a[4],a[5], b[2],b[3]); cmad(r6,r7, a[6],a[7], b[6],b[7]);
    o[0]=r0; o[1]=r1; o[2]=r2; o[3]=r3; o[4]=r4; o[5]=r5; o[6]=r6; o[7]=r7;
}

// ---------------- commutator (traceless operands) ----------------
// [A,W] with A traceless (u6 = {A00, A01, A10}); W given by off-diagonals
// W01, W10 and diagonal difference dW = W00 - W11. Result traceless:
//   C00 = A01*W10 - A10*W01 ; C01 = W01*dA - A01*dW ; C10 = A10*dW - W10*dA
// where dA = 2*A00.
__device__ __forceinline__ void comm_core2(const float* u6,
        float w01r, float w01i, float w10r, float w10i,
        float dwr, float dwi, float* o6) {
    const float dar = 2.f * u6[0], dai = 2.f * u6[1];
    float ar, ai;
    cmul (ar, ai, u6[2],u6[3], w10r,w10i);     // A01*W10
    cmsub(ar, ai, u6[4],u6[5], w01r,w01i);     // - A10*W01
    o6[0] = ar; o6[1] = ai;
    cmul (ar, ai, w01r,w01i, dar,dai);         // W01*dA
    cmsub(ar, ai, u6[2],u6[3], dwr,dwi);       // - A01*dW
    o6[2] = ar; o6[3] = ai;
    cmul (ar, ai, u6[4],u6[5], dwr,dwi);       // A10*dW
    cmsub(ar, ai, w10r,w10i, dar,dai);         // - W10*dA
    o6[4] = ar; o6[5] = ai;
}

// dexp^{-1}_{s*k}(w), order 4, Bernoulli (1,-1/2,1/6,0,-1/30).
// Cayley-Hamilton collapse: for traceless u in sl(2,C), ad_u^3 = 4*w_k*ad_u
// (exact identity; ad eigenvalues {0,0,+-2*delta}, w_k = delta^2 = u00^2
//  + u01*u10). Hence ad^4 = 4*w_k*ad^2 and the order-4 series is
//   res = w + c1*ad(w) + (c2 + 4*c4*w_k)*ad^2(w),  coefficient complex.
// Identical result to the 4-commutator chain, at half the ops and depth.
__device__ __forceinline__ void dexpinv8(const float* k, const float* w,
                                         float s, float* o) {
    float u6[6];
    u6[0] = 0.5f*(k[0]-k[6]); u6[1] = 0.5f*(k[1]-k[7]);
    u6[2] = k[2]; u6[3] = k[3]; u6[4] = k[4]; u6[5] = k[5];
    float a1[6], a2[6];
    comm_core2(u6, w[2],w[3], w[4],w[5], w[0]-w[6], w[1]-w[7], a1);   // ad^1
    comm_core2(u6, a1[2],a1[3], a1[4],a1[5], 2.f*a1[0], 2.f*a1[1], a2); // ad^2
    // w_k = u00^2 + u01*u10  (complex, unscaled k)
    float wkr = fmaf(u6[0],u6[0], -(u6[1]*u6[1]));
    wkr = fmaf(u6[2], u6[4], wkr); wkr = fmaf(-u6[3], u6[5], wkr);
    float wki = 2.f*u6[0]*u6[1];
    wki = fmaf(u6[2], u6[5], wki); wki = fmaf(u6[3], u6[4], wki);
    const float s2  = s*s;
    const float c1  = -0.5f*s;
    const float c2  = s2*(1.f/12.f);
    const float c4m = -(s2*s2)*(1.f/180.f);   // 4*c4 = -4 s^4/720
    const float gr = fmaf(c4m, wkr, c2), gi = c4m*wki;
    float acc[6];
#pragma unroll
    for (int p = 0; p < 3; ++p) {
        const float a2r = a2[2*p], a2i = a2[2*p+1];
        acc[2*p]   = fmaf(gr, a2r, fmaf(-gi, a2i, c1*a1[2*p]));
        acc[2*p+1] = fmaf(gr, a2i, fmaf( gi, a2r, c1*a1[2*p+1]));
    }
    o[0] = w[0] + acc[0]; o[1] = w[1] + acc[1];
    o[2] = w[2] + acc[2]; o[3] = w[3] + acc[3];
    o[4] = w[4] + acc[4]; o[5] = w[5] + acc[5];
    o[6] = w[6] - acc[0]; o[7] = w[7] - acc[1];
}

// ---------------- closed-form exp ----------------
// exp(s*k) = e^{c0} (cosh(d) I + sinhc(d) V), c0 = central part, V traceless,
// d^2 = w = V00^2 + V01*V10. cosh/sinhc as entire series in w.
// FAST (z-stages, |w| <~ 0.3): 3 terms, trunc err <= w^3/720 ~ 4e-5.
// FULL (final exp, clipped u):  5 terms.
__device__ __forceinline__ void chstep(float& pr, float& pi,
                                       float wr, float wi, float K) {
    const float nr = fmaf(pr, wr, fmaf(-pi, wi, K));
    const float ni = fmaf(pr, wi, pi * wr);
    pr = nr; pi = ni;
}
template<bool FULL>
__device__ __forceinline__ void expm(const float* k, float s, float* o) {
    const float hs = 0.5f * s;
    const float c0r = hs*(k[0]+k[6]), c0i = hs*(k[1]+k[7]);
    const float v0r = hs*(k[0]-k[6]), v0i = hs*(k[1]-k[7]);
    const float v1r = s*k[2], v1i = s*k[3];
    const float v2r = s*k[4], v2i = s*k[5];
    float wr = fmaf(v0r, v0r, -(v0i*v0i));
    wr = fmaf(v1r, v2r, wr); wr = fmaf(-v1i, v2i, wr);
    float wi = 2.f*v0r*v0i;
    wi = fmaf(v1r, v2i, wi); wi = fmaf(v1i, v2r, wi);
    float Cr, Ci = 0.f, Sr, Si = 0.f;
    if (FULL) {
        Cr = 1.f/40320.f;                      // cosh: 1,1/2,1/24,1/720,1/40320
        chstep(Cr, Ci, wr, wi, 1.f/720.f);
        chstep(Cr, Ci, wr, wi, 1.f/24.f);
        chstep(Cr, Ci, wr, wi, 0.5f);
        chstep(Cr, Ci, wr, wi, 1.f);
        Sr = 1.f/362880.f;                     // sinhc: 1,1/6,1/120,1/5040,1/362880
        chstep(Sr, Si, wr, wi, 1.f/5040.f);
        chstep(Sr, Si, wr, wi, 1.f/120.f);
        chstep(Sr, Si, wr, wi, 1.f/6.f);
        chstep(Sr, Si, wr, wi, 1.f);
    } else {
        Cr = 1.f/24.f;                         // cosh: 1,1/2,1/24
        chstep(Cr, Ci, wr, wi, 0.5f);
        chstep(Cr, Ci, wr, wi, 1.f);
        Sr = 1.f/120.f;                        // sinhc: 1,1/6,1/120
        chstep(Sr, Si, wr, wi, 1.f/6.f);
        chstep(Sr, Si, wr, wi, 1.f);
    }
    const float ex = __expf(c0r);
    const float cs = __cosf(c0i), sn = __sinf(c0i);
    const float er = ex*cs, ei = ex*sn;        // e^{c0}
    float p0r, p0i; cmul(p0r, p0i, Sr, Si, v0r, v0i);     // S*V00
    const float tr = Cr + p0r, ti = Ci + p0i;
    const float ur = Cr - p0r, ui = Ci - p0i;
    cmul(o[0], o[1], er, ei, tr, ti);
    cmul(o[6], o[7], er, ei, ur, ui);
    float qr, qi; cmul(qr, qi, er, ei, Sr, Si);           // e^{c0}*S
    cmul(o[2], o[3], qr, qi, v1r, v1i);
    cmul(o[4], o[5], qr, qi, v2r, v2i);
}

// ---------------- LDS access (b128-vectorized, bank-swizzled) ----------------
__device__ __forceinline__ int sbase(int e) { return (e << 3) ^ (e & 4); }

__device__ __forceinline__ void lds_load8(const float* buf, int e, float* o) {
    const int b = sbase(e);
    float4 a = *(const float4*)(buf + b);
    float4 c = *(const float4*)(buf + (b ^ 4));
    o[0] = a.x; o[1] = a.y; o[2] = a.z; o[3] = a.w;
    o[4] = c.x; o[5] = c.y; o[6] = c.z; o[7] = c.w;
}
__device__ __forceinline__ void lds_store8(float* buf, int e, const float* v) {
    const int b = sbase(e);
    *(float4*)(buf + b)       = make_float4(v[0], v[1], v[2], v[3]);
    *(float4*)(buf + (b ^ 4)) = make_float4(v[4], v[5], v[6], v[7]);
}

// vector_field (matrix rep): derivative map + ISCL * z0 * bc
__device__ __forceinline__ void vf8_lds(const float* buf, int e, float* o) {
    float z0[8], t1[8], t2[8], t4[8], t8[8], bc[8], g[8];
    lds_load8(buf, e,     z0);
    lds_load8(buf, e + 1, t1);
    lds_load8(buf, e + 2, t2);
    lds_load8(buf, e + 4, t4);
    lds_load8(buf, e + 8, t8);
#pragma unroll
    for (int c = 0; c < 8; ++c)
        bc[c] = fmaf(0.125f, t8[c], fmaf(0.25f, t4[c], fmaf(0.5f, t2[c], t1[c])));
    mm2(z0, bc, g);
    const float Sr  = z0[2]+z0[4], Si  = z0[3]+z0[5];   // M01+M10
    const float Ddr = z0[0]-z0[6], Ddi = z0[1]-z0[7];   // M00-M11
    const float Tr  = z0[4]-z0[2], Ti  = z0[5]-z0[3];   // M10-M01
    o[0] = fmaf(ISCL, g[0],  0.5f*Si);
    o[1] = fmaf(ISCL, g[1], -0.5f*Sr);
    o[2] = fmaf(ISCL, g[2],  0.5f*(Ddi+Ti));
    o[3] = fmaf(ISCL, g[3], -0.5f*(Ddr+Tr));
    o[4] = fmaf(ISCL, g[4],  0.5f*(Ddi-Ti));
    o[5] = fmaf(ISCL, g[5], -0.5f*(Ddr-Tr));
    o[6] = fmaf(ISCL, g[6], -0.5f*Si);
    o[7] = fmaf(ISCL, g[7],  0.5f*Sr);
}

// z = exp(scale*k) * y[e] -> zbuf[e]  (fast 3-term exp: z-stage scales only)
__device__ __forceinline__ void zstage(const float* ybuf, float* zbuf, int e,
                                       const float* k, float scale) {
    float ex[8], yv[8], o[8];
    expm<false>(k, scale, ex);
    lds_load8(ybuf, e, yv);
    mm2(ex, yv, o);
    lds_store8(zbuf, e, o);
}

// kout = dexpinv(scale*kin, vf(z[e]))
__device__ __forceinline__ void kstage(const float* zbuf, int e,
                                       const float* kin, float scale, float* kout) {
    float w[8];
    vf8_lds(zbuf, e, w);
    dexpinv8(kin, w, scale, kout);
}

__global__ __launch_bounds__(CC, 4)
void clifford_step_kernel(const float* __restrict__ y, float* __restrict__ out) {
    __shared__ __align__(16) float sy[NY * SP];   // 9248 B (matrix rep)
    __shared__ __align__(16) float sz[NZ * SP];   // 8992 B

    const int tid   = threadIdx.x;
    const int row   = blockIdx.x >> 8;      // 65536/256 = 256 chunks per row
    const int chunk = blockIdx.x & 255;
    const int base  = chunk * CC;
    // rotate the halo-heavy wave per block so heavy waves spread across SIMDs
    const int bt    = (tid - ((blockIdx.x & 3) << 6)) & 255;
    const float* __restrict__ yrow = y + (size_t)row * 65536u * 8u;

    // ---- load y tile (+halo 32) into LDS, converting mv -> matrix ----
    {
        const int g0 = (base + tid) & 65535;
        const float4* p = (const float4*)(yrow + (size_t)g0 * 8u);
        float4 A = p[0], B = p[1];     // a0..a3 | a4..a7
        const int s = sbase(tid);
        *(float4*)&sy[s]     = make_float4(A.x + A.w, B.w + B.x, A.y - B.y, B.z - A.z);
        *(float4*)&sy[s ^ 4] = make_float4(A.y + B.y, B.z + A.z, A.x - A.w, B.w - B.x);
        if (bt < NY - CC) {
            const int e  = CC + bt;
            const int g1 = (base + e) & 65535;
            const float4* q = (const float4*)(yrow + (size_t)g1 * 8u);
            float4 Cv = q[0], D = q[1];
            const int s2 = sbase(e);
            *(float4*)&sy[s2]     = make_float4(Cv.x + Cv.w, D.w + D.x, Cv.y - D.y, D.z - Cv.z);
            *(float4*)&sy[s2 ^ 4] = make_float4(Cv.y + D.y, D.z + Cv.z, Cv.x - Cv.w, D.w - D.x);
        }
    }
    __syncthreads();

    // ---- rolling state: ka/kb = current k, uacc = k1 + 2k2 + 2k3 (+k4) ----
    float ka[8], kb[8], uacc[8], kn[8];

    // k1
    vf8_lds(sy, tid, ka);
#pragma unroll
    for (int c = 0; c < 8; ++c) uacc[c] = ka[c];
    if (bt < NZ - CC) vf8_lds(sy, CC + bt, kb);

    // z2 = exp(0.05*k1) * y
    zstage(sy, sz, tid, ka, 0.05f);
    if (bt < NZ - CC) zstage(sy, sz, CC + bt, kb, 0.05f);
    __syncthreads();                         // RAW on sz

    // k2 = dexpinv(0.05*k1, vf(z2))
    kstage(sz, tid, ka, 0.05f, kn);
#pragma unroll
    for (int c = 0; c < 8; ++c) { ka[c] = kn[c]; uacc[c] = fmaf(2.f, kn[c], uacc[c]); }
    if (bt < NK2 - CC) {
        kstage(sz, CC + bt, kb, 0.05f, kn);
#pragma unroll
        for (int c = 0; c < 8; ++c) kb[c] = kn[c];
    }
    __syncthreads();                         // WAR: z3 overwrites sz

    // z3 = exp(0.05*k2) * y
    zstage(sy, sz, tid, ka, 0.05f);
    if (bt < NK2 - CC) zstage(sy, sz, CC + bt, kb, 0.05f);
    __syncthreads();                         // RAW on sz

    // k3 = dexpinv(0.05*k2, vf(z3))
    kstage(sz, tid, ka, 0.05f, kn);
#pragma unroll
    for (int c = 0; c < 8; ++c) { ka[c] = kn[c]; uacc[c] = fmaf(2.f, kn[c], uacc[c]); }
    if (bt < NK3 - CC) {
        kstage(sz, CC + bt, kb, 0.05f, kn);
#pragma unroll
        for (int c = 0; c < 8; ++c) kb[c] = kn[c];
    }
    __syncthreads();                         // WAR: z4 overwrites sz

    // z4 = exp(0.1*k3) * y
    zstage(sy, sz, tid, ka, 0.1f);
    if (bt < NK3 - CC) zstage(sy, sz, CC + bt, kb, 0.1f);
    __syncthreads();                         // RAW on sz

    // ---- tail: k4, u (sanitized in mv basis), output ----
    {
        const int e = tid;
        float w[8], k4[8], um[8], ex[8], yv[8], om[8];
        vf8_lds(sz, e, w);
        dexpinv8(ka, w, 0.1f, k4);           // ka == k3

        const float s6 = 0.1f / 6.0f;
#pragma unroll
        for (int c = 0; c < 8; ++c)
            um[c] = s6 * (uacc[c] + k4[c]);
        // matrix -> multivector coeffs, nan_to_num + clip, -> matrix
        float av[8];
        av[0] = 0.5f*(um[0]+um[6]); av[3] = 0.5f*(um[0]-um[6]);
        av[7] = 0.5f*(um[1]+um[7]); av[4] = 0.5f*(um[1]-um[7]);
        av[1] = 0.5f*(um[2]+um[4]); av[5] = 0.5f*(um[4]-um[2]);
        av[6] = 0.5f*(um[3]+um[5]); av[2] = 0.5f*(um[5]-um[3]);
#pragma unroll
        for (int c = 0; c < 8; ++c) {
            float v = av[c];
            if (isnan(v)) v = 0.f;           // nan_to_num(nan=0); clip handles +-inf
            av[c] = fmaxf(-1.f, fminf(v, 1.f));
        }
        um[0] = av[0]+av[3]; um[1] = av[7]+av[4];
        um[2] = av[1]-av[5]; um[3] = av[6]-av[2];
        um[4] = av[1]+av[5]; um[5] = av[6]+av[2];
        um[6] = av[0]-av[3]; um[7] = av[7]-av[4];

        expm<true>(um, 1.f, ex);
        lds_load8(sy, e, yv);
        mm2(ex, yv, om);

        float* dst = out + ((size_t)row * 65536u + (size_t)(base + e)) * 8u;
        ((float4*)dst)[0] = make_float4(0.5f*(om[0]+om[6]), 0.5f*(om[2]+om[4]),
                                        0.5f*(om[5]-om[3]), 0.5f*(om[0]-om[6]));
        ((float4*)dst)[1] = make_float4(0.5f*(om[1]-om[7]), 0.5f*(om[4]-om[2]),
                                        0.5f*(om[3]+om[5]), 0.5f*(om[1]+om[7]));
    }
}

extern "C" void kernel_launch(void* const* d_in, const int* in_sizes, int n_in,
                              void* d_out, int out_size, void* d_ws, size_t ws_size,
                              hipStream_t stream) {
    const float* y = (const float*)d_in[0];
    float* out = (float*)d_out;
    dim3 grid(32 * 256);   // 32 rows x 256 chunks of 256 elements
    dim3 block(CC);
    hipLaunchKernelGGL(clifford_step_kernel, grid, block, 0, stream, y, out);
}